// Round 1
// baseline (403.851 us; speedup 1.0000x reference)
//
#include <hip/hip_runtime.h>
#include <hip/hip_bf16.h>

#define NROW 1024

__device__ __forceinline__ float wave_reduce(float v) {
    for (int off = 32; off; off >>= 1) v += __shfl_down(v, off);
    return v;
}

// out[i,c] = sum_k in[i,k] * W[k,c]; one block per row i, blockDim = F threads.
__global__ void gemm_rowblock(const float* __restrict__ in, const float* __restrict__ W,
                              float* __restrict__ out, int K, int F) {
    __shared__ float srow[512];
    int i = blockIdx.x;
    for (int k = threadIdx.x; k < K; k += blockDim.x) srow[k] = in[i * K + k];
    __syncthreads();
    int c = threadIdx.x;
    float acc = 0.f;
    for (int k = 0; k < K; ++k) acc = fmaf(srow[k], W[k * F + c], acc);
    out[i * F + c] = acc;
}

// blocks [0,512): e1 rows (2 rows per block, one per wave). blocks [512,512+G): E2 rows.
template <int F, int G>
__global__ void e1E2_kernel(const float* __restrict__ h, const float* __restrict__ a,
                            float* __restrict__ e1, float* __restrict__ E2) {
    int t = threadIdx.x;
    if (blockIdx.x < 512) {
        int wave = t >> 6, lane = t & 63;
        int j = blockIdx.x * 2 + wave;
        float p = 0.f;
        for (int k = lane; k < F; k += 64) p = fmaf(h[j * F + k], a[k], p);
        p = wave_reduce(p);
        if (lane == 0) e1[j] = p;
    } else {
        int ib = (int)blockIdx.x - 512;
        if (t < F) {
            float acc = 0.f;
            for (int p = 0; p < F; ++p) acc = fmaf(a[F + p], h[(p * G + ib) * F + t], acc);
            E2[ib * F + t] = acc;
        }
    }
}

// wexp[ib*1024 + j] = exp(leaky_relu(e1[j] + E2[ib, j % F]))
template <int F>
__global__ void wexp_kernel(const float* __restrict__ e1, const float* __restrict__ E2,
                            float* __restrict__ wexp) {
    int idx = blockIdx.x * 256 + threadIdx.x;
    int ib = idx >> 10, j = idx & 1023;
    float v = e1[j] + E2[ib * F + (j & (F - 1))];
    v = v > 0.f ? v : 0.2f * v;
    wexp[idx] = expf(v);
}

// out[i,:] = relu( relu( (1/s_i) * sum_j adj[i,j]*w[ib,j]*h[j,:] ) + b )
template <int F>
__global__ void __launch_bounds__(256) attn_kernel(const float* __restrict__ h,
                                                   const int* __restrict__ adj,
                                                   const float* __restrict__ wexp,
                                                   const float* __restrict__ b,
                                                   float* __restrict__ out) {
    constexpr int NQ = 256 / F;
    __shared__ float alpha[NROW];
    __shared__ float wred[4];
    __shared__ float cred[256];
    __shared__ float sinv_sh;
    int i = blockIdx.x;
    int ib = i / F;
    int t = threadIdx.x;
    const int* arow = adj + i * NROW;
    const float* wrow = wexp + ib * NROW;
    float sp = 0.f;
    for (int j = t; j < NROW; j += 256) {
        float w = arow[j] > 0 ? wrow[j] : 0.f;
        alpha[j] = w;
        sp += w;
    }
    sp = wave_reduce(sp);
    int lane = t & 63, wv = t >> 6;
    if (lane == 0) wred[wv] = sp;
    __syncthreads();
    if (t == 0) sinv_sh = 1.0f / (wred[0] + wred[1] + wred[2] + wred[3]);
    __syncthreads();
    int c = t & (F - 1);
    int q = t / F;
    float acc = 0.f;
    for (int j = q; j < NROW; j += NQ) acc = fmaf(alpha[j], h[j * F + c], acc);
    cred[t] = acc;
    __syncthreads();
    if (q == 0) {
        float tot = 0.f;
#pragma unroll
        for (int qq = 0; qq < NQ; ++qq) tot += cred[qq * F + c];
        float v = tot * sinv_sh;
        v = v > 0.f ? v : 0.f;
        v += b[c];
        v = v > 0.f ? v : 0.f;
        out[i * F + c] = v;
    }
}

// t1[row] = relu(l1w[row,:] . xf + l1b[row]); row in [0, 6*256)
__global__ void __launch_bounds__(256) head1_kernel(const float* __restrict__ l1w,
                                                    const float* __restrict__ l1b,
                                                    const float* __restrict__ xf,
                                                    float* __restrict__ t1) {
    __shared__ float red[4];
    int row = blockIdx.x;
    const float4* wrow = (const float4*)(l1w) + (size_t)row * 16384;
    const float4* xv = (const float4*)xf;
    float acc = 0.f;
    for (int it = threadIdx.x; it < 16384; it += 256) {
        float4 w = wrow[it];
        float4 x = xv[it];
        acc = fmaf(w.x, x.x, fmaf(w.y, x.y, fmaf(w.z, x.z, fmaf(w.w, x.w, acc))));
    }
    acc = wave_reduce(acc);
    int lane = threadIdx.x & 63, wv = threadIdx.x >> 6;
    if (lane == 0) red[wv] = acc;
    __syncthreads();
    if (threadIdx.x == 0) {
        float s = red[0] + red[1] + red[2] + red[3] + l1b[row];
        t1[row] = s > 0.f ? s : 0.f;
    }
}

// fused layers 2+3 of head: 6 blocks, 128 threads
__global__ void head23_kernel(const float* __restrict__ l2w, const float* __restrict__ l2b,
                              const float* __restrict__ l3w, const float* __restrict__ l3b,
                              const float* __restrict__ t1, float* __restrict__ out) {
    __shared__ float t2s[128];
    __shared__ float red[2];
    int hh = blockIdx.x, o = threadIdx.x;
    const float* wrow = l2w + (hh * 128 + o) * 256;
    const float* t1h = t1 + hh * 256;
    float acc = 0.f;
    for (int k = 0; k < 256; ++k) acc = fmaf(wrow[k], t1h[k], acc);
    acc += l2b[hh * 128 + o];
    t2s[o] = 1.0f / (1.0f + expf(-acc));
    __syncthreads();
    float p = l3w[hh * 128 + o] * t2s[o];
    p = wave_reduce(p);
    if ((o & 63) == 0) red[o >> 6] = p;
    __syncthreads();
    if (o == 0) out[hh] = red[0] + red[1] + l3b[hh];
}

extern "C" void kernel_launch(void* const* d_in, const int* in_sizes, int n_in,
                              void* d_out, int out_size, void* d_ws, size_t ws_size,
                              hipStream_t stream) {
    const float* x   = (const float*)d_in[0];
    const int*   adj = (const int*)d_in[1];
    const float* W1  = (const float*)d_in[2];
    const float* a1  = (const float*)d_in[3];
    const float* b1  = (const float*)d_in[4];
    const float* W2  = (const float*)d_in[5];
    const float* a2  = (const float*)d_in[6];
    const float* b2  = (const float*)d_in[7];
    const float* W3  = (const float*)d_in[8];
    const float* a3  = (const float*)d_in[9];
    const float* b3  = (const float*)d_in[10];
    const float* l1w = (const float*)d_in[11];
    const float* l1b = (const float*)d_in[12];
    const float* l2w = (const float*)d_in[13];
    const float* l2b = (const float*)d_in[14];
    const float* l3w = (const float*)d_in[15];
    const float* l3b = (const float*)d_in[16];
    float* out = (float*)d_out;

    float* ws = (float*)d_ws;
    float* hA   = ws;            // 1024*128
    float* hB   = ws + 131072;   // 1024*128
    float* hC   = ws + 262144;   // 1024*64
    float* hD   = ws + 327680;   // 1024*64
    float* hE   = ws + 393216;   // 1024*64
    float* xf   = ws + 458752;   // 1024*64
    float* e1   = ws + 524288;   // 1024
    float* E2   = ws + 525312;   // 1024
    float* wexp = ws + 526336;   // 16*1024
    float* t1   = ws + 542720;   // 1536

    // ---- GAT layer 1 (F=128, G=8) ----
    gemm_rowblock<<<NROW, 128, 0, stream>>>(x, W1, hA, 512, 128);
    e1E2_kernel<128, 8><<<512 + 8, 128, 0, stream>>>(hA, a1, e1, E2);
    wexp_kernel<128><<<(8 * NROW) / 256, 256, 0, stream>>>(e1, E2, wexp);
    attn_kernel<128><<<NROW, 256, 0, stream>>>(hA, adj, wexp, b1, hB);

    // ---- GAT layer 2 (F=64, G=16) ----
    gemm_rowblock<<<NROW, 64, 0, stream>>>(hB, W2, hC, 128, 64);
    e1E2_kernel<64, 16><<<512 + 16, 128, 0, stream>>>(hC, a2, e1, E2);
    wexp_kernel<64><<<(16 * NROW) / 256, 256, 0, stream>>>(e1, E2, wexp);
    attn_kernel<64><<<NROW, 256, 0, stream>>>(hC, adj, wexp, b2, hD);

    // ---- GAT layer 3 (F=64, G=16) ----
    gemm_rowblock<<<NROW, 64, 0, stream>>>(hD, W3, hE, 64, 64);
    e1E2_kernel<64, 16><<<512 + 16, 128, 0, stream>>>(hE, a3, e1, E2);
    wexp_kernel<64><<<(16 * NROW) / 256, 256, 0, stream>>>(e1, E2, wexp);
    attn_kernel<64><<<NROW, 256, 0, stream>>>(hE, adj, wexp, b3, xf);

    // ---- head ----
    head1_kernel<<<6 * 256, 256, 0, stream>>>(l1w, l1b, xf, t1);
    head23_kernel<<<6, 128, 0, stream>>>(l2w, l2b, l3w, l3b, t1, out);
}

// Round 2
// 203.514 us; speedup vs baseline: 1.9844x; 1.9844x over previous
//
#include <hip/hip_runtime.h>
#include <hip/hip_bf16.h>

#define NROW 1024

__device__ __forceinline__ float wave_reduce(float v) {
    for (int off = 32; off; off >>= 1) v += __shfl_down(v, off);
    return v;
}

// h[i,:] = in[i,:] @ W ; e1[i] = h[i,:] . a[:F]   (R rows per block, F*R threads)
template <int K, int F, int R>
__global__ void __launch_bounds__(F * R) gemm_e1_kernel(const float* __restrict__ in,
                                                        const float* __restrict__ W,
                                                        const float* __restrict__ a,
                                                        float* __restrict__ h,
                                                        float* __restrict__ e1) {
    __shared__ float srow[R * K];
    __shared__ float red[(F / 64) * R];
    int t = threadIdx.x;
    int i0 = blockIdx.x * R;
    for (int idx = t; idx < R * K; idx += F * R) srow[idx] = in[i0 * K + idx];
    __syncthreads();
    int c = t % F, r = t / F;
    float acc = 0.f;
#pragma unroll 8
    for (int k = 0; k < K; ++k) acc = fmaf(srow[r * K + k], W[k * F + c], acc);
    h[(i0 + r) * F + c] = acc;
    float p = wave_reduce(acc * a[c]);
    int lane = t & 63, wv = t >> 6;
    if (lane == 0) red[wv] = p;
    __syncthreads();
    constexpr int WPR = F / 64;
    if (t < R) {
        float s = 0.f;
#pragma unroll
        for (int w = 0; w < WPR; ++w) s += red[t * WPR + w];
        e1[i0 + t] = s;
    }
}

// Fused: E2 row + wexp + row-sums + att@h + relu + bias + relu, 4 output rows per block.
template <int F, int G>
__global__ void __launch_bounds__(512) attn_fused(const float* __restrict__ h,
                                                  const int* __restrict__ adj,
                                                  const float* __restrict__ e1,
                                                  const float* __restrict__ a,
                                                  const float* __restrict__ b,
                                                  float* __restrict__ out) {
    constexpr int NQ = 512 / F;
    __shared__ float wexp_sh[NROW];
    __shared__ float E2row[F];
    __shared__ float sinv[4];
    __shared__ float red[8];
    __shared__ float cred[512 * 4];
    int t = threadIdx.x;
    int i0 = blockIdx.x * 4;
    int ib = i0 / F;
    // E2 row for this ib: E2[c] = sum_p a[F+p] * h[(p*G+ib)*F + c]
    if (t < F) {
        float acc = 0.f;
#pragma unroll 8
        for (int p = 0; p < F; ++p) acc = fmaf(a[F + p], h[(p * G + ib) * F + t], acc);
        E2row[t] = acc;
    }
    __syncthreads();
    for (int j = t; j < NROW; j += 512) {
        float v = e1[j] + E2row[j & (F - 1)];
        v = v > 0.f ? v : 0.2f * v;
        wexp_sh[j] = expf(v);
    }
    __syncthreads();
    int lane = t & 63, wv = t >> 6;
    {
        int r = wv & 3;
        const int* arow = adj + (size_t)(i0 + r) * NROW;
        float s = 0.f;
        for (int j = (wv >> 2) * 64 + lane; j < NROW; j += 128)
            s += (arow[j] > 0) ? wexp_sh[j] : 0.f;
        s = wave_reduce(s);
        if (lane == 0) red[wv] = s;
    }
    __syncthreads();
    if (t < 4) sinv[t] = 1.f / (red[t] + red[t + 4]);
    __syncthreads();
    int c = t % F, q = t / F;
    const int* a0 = adj + (size_t)(i0 + 0) * NROW;
    const int* a1 = adj + (size_t)(i0 + 1) * NROW;
    const int* a2 = adj + (size_t)(i0 + 2) * NROW;
    const int* a3 = adj + (size_t)(i0 + 3) * NROW;
    float acc0 = 0.f, acc1 = 0.f, acc2 = 0.f, acc3 = 0.f;
#pragma unroll 4
    for (int j = q; j < NROW; j += NQ) {
        float w = wexp_sh[j];
        float hv = h[j * F + c];
        acc0 = fmaf(a0[j] > 0 ? w : 0.f, hv, acc0);
        acc1 = fmaf(a1[j] > 0 ? w : 0.f, hv, acc1);
        acc2 = fmaf(a2[j] > 0 ? w : 0.f, hv, acc2);
        acc3 = fmaf(a3[j] > 0 ? w : 0.f, hv, acc3);
    }
    float* cr = cred + t * 4;
    cr[0] = acc0; cr[1] = acc1; cr[2] = acc2; cr[3] = acc3;
    __syncthreads();
    if (t < 4 * F) {
        int rr = t / F, cc = t % F;
        float tot = 0.f;
#pragma unroll
        for (int qq = 0; qq < NQ; ++qq) tot += cred[(qq * F + cc) * 4 + rr];
        float v = tot * sinv[rr];
        v = v > 0.f ? v : 0.f;
        v += b[cc];
        v = v > 0.f ? v : 0.f;
        out[(i0 + rr) * F + cc] = v;
    }
}

// head layer-1 partials: block = (row, half); part[row*2+half] = dot over 32768 elems
__global__ void __launch_bounds__(256) head1p_kernel(const float* __restrict__ l1w,
                                                     const float* __restrict__ xf,
                                                     float* __restrict__ part) {
    __shared__ float red[4];
    int row = blockIdx.x >> 1, half = blockIdx.x & 1;
    const float4* wrow = (const float4*)l1w + (size_t)row * 16384 + half * 8192;
    const float4* xv = (const float4*)xf + half * 8192;
    float acc = 0.f;
#pragma unroll 4
    for (int it = threadIdx.x; it < 8192; it += 256) {
        float4 w = wrow[it];
        float4 x = xv[it];
        acc = fmaf(w.x, x.x, fmaf(w.y, x.y, fmaf(w.z, x.z, fmaf(w.w, x.w, acc))));
    }
    acc = wave_reduce(acc);
    int lane = threadIdx.x & 63, wv = threadIdx.x >> 6;
    if (lane == 0) red[wv] = acc;
    __syncthreads();
    if (threadIdx.x == 0) part[blockIdx.x] = red[0] + red[1] + red[2] + red[3];
}

// reduce head1 partials + bias + relu, then layers 2+3 of head: 6 blocks, 128 threads
__global__ void head23_kernel(const float* __restrict__ part, const float* __restrict__ l1b,
                              const float* __restrict__ l2w, const float* __restrict__ l2b,
                              const float* __restrict__ l3w, const float* __restrict__ l3b,
                              float* __restrict__ out) {
    __shared__ float t1s[256];
    __shared__ float red[2];
    int hh = blockIdx.x, o = threadIdx.x;
    for (int r = o; r < 256; r += 128) {
        int row = hh * 256 + r;
        float s = part[row * 2] + part[row * 2 + 1] + l1b[row];
        t1s[r] = s > 0.f ? s : 0.f;
    }
    __syncthreads();
    const float* wrow = l2w + (size_t)(hh * 128 + o) * 256;
    float acc = 0.f;
#pragma unroll 8
    for (int k = 0; k < 256; ++k) acc = fmaf(wrow[k], t1s[k], acc);
    acc += l2b[hh * 128 + o];
    float t2 = 1.0f / (1.0f + expf(-acc));
    float p = wave_reduce(l3w[hh * 128 + o] * t2);
    if ((o & 63) == 0) red[o >> 6] = p;
    __syncthreads();
    if (o == 0) out[hh] = red[0] + red[1] + l3b[hh];
}

extern "C" void kernel_launch(void* const* d_in, const int* in_sizes, int n_in,
                              void* d_out, int out_size, void* d_ws, size_t ws_size,
                              hipStream_t stream) {
    const float* x   = (const float*)d_in[0];
    const int*   adj = (const int*)d_in[1];
    const float* W1  = (const float*)d_in[2];
    const float* a1  = (const float*)d_in[3];
    const float* b1  = (const float*)d_in[4];
    const float* W2  = (const float*)d_in[5];
    const float* a2  = (const float*)d_in[6];
    const float* b2  = (const float*)d_in[7];
    const float* W3  = (const float*)d_in[8];
    const float* a3  = (const float*)d_in[9];
    const float* b3  = (const float*)d_in[10];
    const float* l1w = (const float*)d_in[11];
    const float* l1b = (const float*)d_in[12];
    const float* l2w = (const float*)d_in[13];
    const float* l2b = (const float*)d_in[14];
    const float* l3w = (const float*)d_in[15];
    const float* l3b = (const float*)d_in[16];
    float* out = (float*)d_out;

    float* ws = (float*)d_ws;
    float* h1   = ws;            // 1024*128
    float* o1   = ws + 131072;   // 1024*128
    float* h2   = ws + 262144;   // 1024*64
    float* o2   = ws + 327680;   // 1024*64
    float* h3   = ws + 393216;   // 1024*64
    float* xf   = ws + 458752;   // 1024*64
    float* e1b  = ws + 524288;   // 1024
    float* part = ws + 525312;   // 3072

    // ---- GAT layer 1 (K=512, F=128, G=8) ----
    gemm_e1_kernel<512, 128, 4><<<256, 512, 0, stream>>>(x, W1, a1, h1, e1b);
    attn_fused<128, 8><<<256, 512, 0, stream>>>(h1, adj, e1b, a1, b1, o1);

    // ---- GAT layer 2 (K=128, F=64, G=16) ----
    gemm_e1_kernel<128, 64, 4><<<256, 256, 0, stream>>>(o1, W2, a2, h2, e1b);
    attn_fused<64, 16><<<256, 512, 0, stream>>>(h2, adj, e1b, a2, b2, o2);

    // ---- GAT layer 3 (K=64, F=64, G=16) ----
    gemm_e1_kernel<64, 64, 4><<<256, 256, 0, stream>>>(o2, W3, a3, h3, e1b);
    attn_fused<64, 16><<<256, 512, 0, stream>>>(h3, adj, e1b, a3, b3, xf);

    // ---- head ----
    head1p_kernel<<<6 * 256 * 2, 256, 0, stream>>>(l1w, xf, part);
    head23_kernel<<<6, 128, 0, stream>>>(part, l1b, l2w, l2b, l3w, l3b, out);
}